// Round 1
// baseline (6408.172 us; speedup 1.0000x reference)
//
#include <hip/hip_runtime.h>
#include <math.h>

#define NA   8192
#define FEAT 100
#define KNN  28
#define NE   (NA*KNN)

__device__ __forceinline__ float sspf(float x){
  // shifted softplus: log(1+exp(x)) - log(2), stable form
  return fmaxf(x, 0.0f) + log1pf(expf(-fabsf(x))) - 0.69314718056f;
}

// ---------------------------------------------------------------------------
// KNN graph: molecules are fixed 32-atom blocks. Per atom: distances to its 31
// peers (clamped to cutoff), keep the 28 smallest (drop self + 3 largest).
// Clamped (==6.0) edges have ccut ~= 0 so selection among ties is irrelevant.
// ---------------------------------------------------------------------------
__global__ __launch_bounds__(64) void build_graph(const float* __restrict__ pos,
    int* __restrict__ src, float* __restrict__ ew, float* __restrict__ ccut)
{
  __shared__ float sp[64][3];
  int tid = threadIdx.x;
  int a = blockIdx.x*64 + tid;
  sp[tid][0] = pos[a*3+0];
  sp[tid][1] = pos[a*3+1];
  sp[tid][2] = pos[a*3+2];
  __syncthreads();
  int lb = tid & 32;          // local molecule base within block (0 or 32)
  int li = tid & 31;          // index within molecule
  float px = sp[tid][0], py = sp[tid][1], pz = sp[tid][2];
  float d[32];
  #pragma unroll
  for (int j = 0; j < 32; j++){
    float dx = px - sp[lb+j][0];
    float dy = py - sp[lb+j][1];
    float dz = pz - sp[lb+j][2];
    float d2 = dx*dx + dy*dy + dz*dz;
    float dist = (d2 > 36.0f) ? 6.0f : sqrtf(d2);
    d[j] = (j == li) ? 1e30f : dist;   // self forced to be dropped
  }
  unsigned dropped = 0u;
  for (int r = 0; r < 4; r++){         // drop 4 largest (self + 3)
    float mx = -1.0f; int mj = 0;
    #pragma unroll
    for (int j = 0; j < 32; j++){
      bool ok = !((dropped >> j) & 1u) && (d[j] > mx);
      mx = ok ? d[j] : mx;
      mj = ok ? j  : mj;
    }
    dropped |= (1u << mj);
  }
  int mol  = a & ~31;
  int base = a*KNN;
  int k = 0;
  #pragma unroll
  for (int j = 0; j < 32; j++){
    if ((dropped >> j) & 1u) continue;
    src[base+k]  = mol + j;
    ew[base+k]   = d[j];
    ccut[base+k] = 0.5f*(cosf(d[j]*(3.14159265358979f/6.0f)) + 1.0f);
    k++;
  }
}

__global__ __launch_bounds__(256) void h_init(const int* __restrict__ z,
    const float* __restrict__ emb, float* __restrict__ h)
{
  int idx = blockIdx.x*256 + threadIdx.x;
  if (idx < NA*FEAT){
    int a = idx/FEAT, f = idx - a*FEAT;
    h[idx] = emb[z[a]*FEAT + f];
  }
}

// ---------------------------------------------------------------------------
// Edge filter MLP + CFConv aggregation. One wave per target atom (4 waves per
// block). 28 edges processed as 7 sub-batches of 4. Lane owns feats
// {lane, lane+64 (if <100)}. W1^T/W2^T staged in LDS, all reads float4.
// agg[i][f] = sum_k x1[src][f] * ccut * (ssp(ea@W1+b1)@W2 + b2)[f]
// LDS: 11200 + 40000 + 800 + 1792 + 6400 = 60192 B -> 2 blocks/CU.
// ---------------------------------------------------------------------------
#define NB 4
__global__ __launch_bounds__(256) void edge_kernel(
    const float* __restrict__ ew, const float* __restrict__ ccut,
    const int*   __restrict__ src, const float* __restrict__ x1,
    const float* __restrict__ W1, const float* __restrict__ b1,
    const float* __restrict__ W2, const float* __restrict__ b2,
    float* __restrict__ agg)
{
  __shared__ __align__(16) float sW1t[100*28];   // [f][g], g padded 25->28
  __shared__ __align__(16) float sW2t[100*100];  // [f][c]
  __shared__ float sb1[100], sb2[100];
  __shared__ __align__(16) float sEA[4][NB*28];  // per-wave [e][g] stride 28
  __shared__ __align__(16) float sT[4][NB*100];  // per-wave [e][c]

  int tid = threadIdx.x, lane = tid & 63, wv = tid >> 6;

  for (int idx = tid; idx < 100*28; idx += 256) sW1t[idx] = 0.0f;
  __syncthreads();
  for (int idx = tid; idx < 2500; idx += 256){
    int g = idx/100, f = idx - g*100;
    sW1t[f*28+g] = W1[idx];
  }
  for (int idx = tid; idx < 10000; idx += 256){
    int c = idx/100, f = idx - c*100;
    sW2t[f*100+c] = W2[idx];
  }
  if (tid < 100){ sb1[tid] = b1[tid]; sb2[tid] = b2[tid]; }
  __syncthreads();

  int atom = blockIdx.x*4 + wv;
  int f0 = lane;
  bool f1v = lane < 36;
  int f1 = f1v ? lane + 64 : lane;   // invalid lanes duplicate f0 (masked stores)
  float acc0 = 0.0f, acc1 = 0.0f;
  int ebase0 = atom*KNN;

  for (int b = 0; b < 7; b++){
    int ebase = ebase0 + b*NB;
    // stage gaussian features for this sub-batch (pad cols 25..27 = 0)
    for (int idx = lane; idx < NB*28; idx += 64){
      int e = idx/28, g = idx - e*28;
      float v = 0.0f;
      if (g < 25){
        float dd = ew[ebase+e] - 0.25f*(float)g;
        v = expf(-8.0f*dd*dd);
      }
      sEA[wv][idx] = v;
    }
    __syncthreads();
    // layer 1: T = ssp(EA @ W1 + b1)
    float tv0[NB], tv1[NB];
    #pragma unroll
    for (int e = 0; e < NB; e++){ tv0[e] = sb1[f0]; tv1[e] = sb1[f1]; }
    #pragma unroll
    for (int gb = 0; gb < 7; gb++){
      float4 w0 = *(const float4*)&sW1t[f0*28 + gb*4];
      float4 w1 = *(const float4*)&sW1t[f1*28 + gb*4];
      #pragma unroll
      for (int e = 0; e < NB; e++){
        float4 ea = *(const float4*)&sEA[wv][e*28 + gb*4];
        tv0[e] += ea.x*w0.x + ea.y*w0.y + ea.z*w0.z + ea.w*w0.w;
        tv1[e] += ea.x*w1.x + ea.y*w1.y + ea.z*w1.z + ea.w*w1.w;
      }
    }
    #pragma unroll
    for (int e = 0; e < NB; e++){
      sT[wv][e*100+f0] = sspf(tv0[e]);
      if (f1v) sT[wv][e*100+f1] = sspf(tv1[e]);
    }
    __syncthreads();
    // layer 2: Wf = T @ W2 + b2, then msg = x1[src]*ccut*Wf, accumulate
    float wf0[NB], wf1[NB];
    #pragma unroll
    for (int e = 0; e < NB; e++){ wf0[e] = sb2[f0]; wf1[e] = sb2[f1]; }
    for (int cb = 0; cb < 25; cb++){
      float4 w0 = *(const float4*)&sW2t[f0*100 + cb*4];
      float4 w1 = *(const float4*)&sW2t[f1*100 + cb*4];
      #pragma unroll
      for (int e = 0; e < NB; e++){
        float4 t = *(const float4*)&sT[wv][e*100 + cb*4];   // broadcast
        wf0[e] += t.x*w0.x + t.y*w0.y + t.z*w0.z + t.w*w0.w;
        wf1[e] += t.x*w1.x + t.y*w1.y + t.z*w1.z + t.w*w1.w;
      }
    }
    #pragma unroll
    for (int e = 0; e < NB; e++){
      float cc = ccut[ebase+e];
      int s = src[ebase+e];
      acc0 += x1[s*FEAT+f0]*cc*wf0[e];
      if (f1v) acc1 += x1[s*FEAT+f1]*cc*wf1[e];
    }
    __syncthreads();
  }
  agg[atom*FEAT+f0] = acc0;
  if (f1v) agg[atom*FEAT+f1] = acc1;
}

// ---------------------------------------------------------------------------
// Node-side linear: Y = op(X @ W [+ b]). MODE 0: Y = X@W. MODE 1: Y = ssp(X@W+b).
// MODE 2: Y += X@W + b (residual h update). Wave handles 8 atoms; W^T in LDS.
// LDS: 40000 + 400 + 12800 = 53.2 KB.
// ---------------------------------------------------------------------------
template<int MODE>
__global__ __launch_bounds__(256) void node_linear(
    const float* __restrict__ X, const float* __restrict__ W,
    const float* __restrict__ bias, float* __restrict__ Y)
{
  __shared__ __align__(16) float sWt[100*100];   // [f][c]
  __shared__ float sB[100];
  __shared__ __align__(16) float sX[4][8*100];
  int tid = threadIdx.x, lane = tid & 63, wv = tid >> 6;
  for (int idx = tid; idx < 10000; idx += 256){
    int c = idx/100, f = idx - c*100;
    sWt[f*100+c] = W[idx];
  }
  if (tid < 100){
    if constexpr (MODE == 0) sB[tid] = 0.0f;
    else                     sB[tid] = bias[tid];
  }
  __syncthreads();
  int base = (blockIdx.x*4 + wv)*8;
  const float4* xg = (const float4*)(X + base*FEAT);
  for (int idx = lane; idx < 200; idx += 64)
    ((float4*)sX[wv])[idx] = xg[idx];
  __syncthreads();
  int f0 = lane;
  bool f1v = lane < 36;
  int f1 = f1v ? lane + 64 : lane;
  float a0[8], a1[8];
  #pragma unroll
  for (int a = 0; a < 8; a++){ a0[a] = sB[f0]; a1[a] = sB[f1]; }
  for (int cb = 0; cb < 25; cb++){
    float4 w0 = *(const float4*)&sWt[f0*100 + cb*4];
    float4 w1 = *(const float4*)&sWt[f1*100 + cb*4];
    #pragma unroll
    for (int a = 0; a < 8; a++){
      float4 x = *(const float4*)&sX[wv][a*100 + cb*4];    // broadcast
      a0[a] += x.x*w0.x + x.y*w0.y + x.z*w0.z + x.w*w0.w;
      a1[a] += x.x*w1.x + x.y*w1.y + x.z*w1.z + x.w*w1.w;
    }
  }
  #pragma unroll
  for (int a = 0; a < 8; a++){
    int row = (base+a)*FEAT;
    float v0 = a0[a], v1 = a1[a];
    if constexpr (MODE == 1){ v0 = sspf(v0); v1 = sspf(v1); }
    if constexpr (MODE == 2){
      Y[row+f0] += v0;
      if (f1v) Y[row+f1] += v1;
    } else {
      Y[row+f0] = v0;
      if (f1v) Y[row+f1] = v1;
    }
  }
}

// ---------------------------------------------------------------------------
// Readout: per molecule (32 atoms): u = ssp(h@w1+b1) [50], pa = u@w2+b2,
// energy = sum over atoms. One wave per molecule.
// ---------------------------------------------------------------------------
__global__ __launch_bounds__(64) void readout(const float* __restrict__ h,
    const float* __restrict__ w1, const float* __restrict__ b1,
    const float* __restrict__ w2, const float* __restrict__ b2,
    float* __restrict__ out)
{
  __shared__ __align__(16) float sW1t[50*100];
  __shared__ __align__(16) float sX[32*100];
  __shared__ float sU[32*52];
  __shared__ float sPA[32];
  __shared__ float sw2[50];
  int lane = threadIdx.x;
  int mol = blockIdx.x;
  for (int idx = lane; idx < 5000; idx += 64){
    int c = idx/50, hf = idx - c*50;
    sW1t[hf*100+c] = w1[idx];
  }
  const float4* xg = (const float4*)(h + mol*32*FEAT);
  for (int idx = lane; idx < 800; idx += 64)
    ((float4*)sX)[idx] = xg[idx];
  if (lane < 50) sw2[lane] = w2[lane];
  __syncthreads();
  int hf = (lane < 50) ? lane : 0;
  bool hv = lane < 50;
  float acc[32];
  #pragma unroll
  for (int a = 0; a < 32; a++) acc[a] = 0.0f;
  for (int cb = 0; cb < 25; cb++){
    float4 w = *(const float4*)&sW1t[hf*100 + cb*4];
    #pragma unroll
    for (int a = 0; a < 32; a++){
      float4 x = *(const float4*)&sX[a*100 + cb*4];        // broadcast
      acc[a] += x.x*w.x + x.y*w.y + x.z*w.z + x.w*w.w;
    }
  }
  float bb = b1[hf];
  if (hv){
    #pragma unroll
    for (int a = 0; a < 32; a++) sU[a*52+hf] = sspf(acc[a] + bb);
  }
  __syncthreads();
  if (lane < 32){
    float pa = b2[0];
    for (int hfi = 0; hfi < 50; hfi++) pa += sU[lane*52+hfi]*sw2[hfi];
    sPA[lane] = pa;
  }
  __syncthreads();
  if (lane == 0){
    float s = 0.0f;
    #pragma unroll
    for (int a = 0; a < 32; a++) s += sPA[a];
    out[mol] = s;
  }
}

extern "C" void kernel_launch(void* const* d_in, const int* in_sizes, int n_in,
                              void* d_out, int out_size, void* d_ws, size_t ws_size,
                              hipStream_t stream)
{
  const int*   z      = (const int*)  d_in[0];
  const float* pos    = (const float*)d_in[1];
  /* d_in[2] = ptr: molecules are fixed 32-atom blocks; unused */
  const float* emb    = (const float*)d_in[3];
  const float* mlp_w1 = (const float*)d_in[4];
  const float* mlp_b1 = (const float*)d_in[5];
  const float* mlp_w2 = (const float*)d_in[6];
  const float* mlp_b2 = (const float*)d_in[7];
  const float* lin1_w = (const float*)d_in[8];
  const float* lin2_w = (const float*)d_in[9];
  const float* lin2_b = (const float*)d_in[10];
  const float* lin_w  = (const float*)d_in[11];
  const float* lin_b  = (const float*)d_in[12];
  const float* out_w1 = (const float*)d_in[13];
  const float* out_b1 = (const float*)d_in[14];
  const float* out_w2 = (const float*)d_in[15];
  const float* out_b2 = (const float*)d_in[16];

  float* ws   = (float*)d_ws;           // total ~16 MB
  float* ew   = ws;                     // [NE]
  float* ccut = ew + NE;                // [NE]
  int*   src  = (int*)(ccut + NE);      // [NE]
  float* h    = (float*)(src + NE);     // [NA*FEAT]
  float* x1   = h   + NA*FEAT;          // [NA*FEAT]
  float* agg  = x1  + NA*FEAT;          // [NA*FEAT]
  float* tmp  = agg + NA*FEAT;          // [NA*FEAT]

  build_graph<<<NA/64, 64, 0, stream>>>(pos, src, ew, ccut);
  h_init<<<(NA*FEAT + 255)/256, 256, 0, stream>>>(z, emb, h);
  for (int l = 0; l < 4; l++){
    node_linear<0><<<256, 256, 0, stream>>>(h, lin1_w + l*10000, nullptr, x1);
    edge_kernel<<<NA/4, 256, 0, stream>>>(ew, ccut, src, x1,
        mlp_w1 + l*2500, mlp_b1 + l*100,
        mlp_w2 + l*10000, mlp_b2 + l*100, agg);
    node_linear<1><<<256, 256, 0, stream>>>(agg, lin2_w + l*10000, lin2_b + l*100, tmp);
    node_linear<2><<<256, 256, 0, stream>>>(tmp, lin_w  + l*10000, lin_b  + l*100, h);
  }
  readout<<<256, 64, 0, stream>>>(h, out_w1, out_b1, out_w2, out_b2, (float*)d_out);
}

// Round 2
// 1565.706 us; speedup vs baseline: 4.0928x; 4.0928x over previous
//
#include <hip/hip_runtime.h>
#include <math.h>

#define NA   8192
#define FEAT 100
#define KNN  28
#define EPP  32              // edges per atom, padded (28 real + 4 dummy ccut=0)
#define NBE  8               // edges per inner batch

__device__ __forceinline__ float sspf(float x){
  // shifted softplus: log(1+exp(x)) - log(2), stable form
  return fmaxf(x, 0.0f) + __logf(1.0f + __expf(-fabsf(x))) - 0.69314718056f;
}

// ---------------------------------------------------------------------------
// KNN graph: molecules are fixed 32-atom blocks. Per atom: distances to its 31
// peers (clamped to cutoff), keep the 28 smallest (drop self + 3 largest).
// Clamped (==6.0) edges have ccut ~= 2e-15 so selection among ties is
// irrelevant at threshold 0.34. Emits 32 edges/atom; 4 dummies (ew=6 -> cc=0).
// ---------------------------------------------------------------------------
__global__ __launch_bounds__(64) void build_graph(const float* __restrict__ pos,
    int* __restrict__ src, float* __restrict__ ew)
{
  __shared__ float sp[64][3];
  int tid = threadIdx.x;
  int a = blockIdx.x*64 + tid;
  sp[tid][0] = pos[a*3+0];
  sp[tid][1] = pos[a*3+1];
  sp[tid][2] = pos[a*3+2];
  __syncthreads();
  int lb = tid & 32;          // local molecule base within block (0 or 32)
  int li = tid & 31;          // index within molecule
  float px = sp[tid][0], py = sp[tid][1], pz = sp[tid][2];
  float d[32];
  #pragma unroll
  for (int j = 0; j < 32; j++){
    float dx = px - sp[lb+j][0];
    float dy = py - sp[lb+j][1];
    float dz = pz - sp[lb+j][2];
    float d2 = dx*dx + dy*dy + dz*dz;
    float dist = (d2 > 36.0f) ? 6.0f : sqrtf(d2);
    d[j] = (j == li) ? 1e30f : dist;   // self forced to be dropped
  }
  unsigned dropped = 0u;
  for (int r = 0; r < 4; r++){         // drop 4 largest (self + 3)
    float mx = -1.0f; int mj = 0;
    #pragma unroll
    for (int j = 0; j < 32; j++){
      bool ok = !((dropped >> j) & 1u) && (d[j] > mx);
      mx = ok ? d[j] : mx;
      mj = ok ? j  : mj;
    }
    dropped |= (1u << mj);
  }
  int mol  = a & ~31;
  int base = a*EPP;
  int k = 0;
  #pragma unroll
  for (int j = 0; j < 32; j++){
    if ((dropped >> j) & 1u) continue;
    src[base+k] = mol + j;
    ew[base+k]  = d[j];
    k++;
  }
  #pragma unroll
  for (int k2 = KNN; k2 < EPP; k2++){  // dummy edges: cc will be 0
    src[base+k2] = a;
    ew[base+k2]  = 6.0f;
  }
}

__global__ __launch_bounds__(256) void h_init(const int* __restrict__ z,
    const float* __restrict__ emb, float* __restrict__ h)
{
  int idx = blockIdx.x*256 + threadIdx.x;
  if (idx < NA*FEAT){
    int a = idx/FEAT, f = idx - a*FEAT;
    h[idx] = emb[z[a]*FEAT + f];
  }
}

// ---------------------------------------------------------------------------
// Edge filter MLP + CFConv aggregation. One wave per target atom (4 waves /
// block). 32 padded edges as 4 batches of 8. Lane owns feats {lane, lane+64}.
// W1^T/W2^T staged once in LDS; per-wave sEA/sT scratch -> NO barriers in the
// batch loop. agg[i][f] = sum_e x1[src][f] * cc * (ssp(ea@W1+b1)@W2 + b2)[f]
// LDS: 11200 + 40000 + 800 + 3584 + 12800 + 3*512 = 69920 B -> 2 blocks/CU.
// ---------------------------------------------------------------------------
__global__ __launch_bounds__(256) void edge_kernel(
    const float* __restrict__ ew, const int* __restrict__ src,
    const float* __restrict__ x1,
    const float* __restrict__ W1, const float* __restrict__ b1,
    const float* __restrict__ W2, const float* __restrict__ b2,
    float* __restrict__ agg)
{
  __shared__ __align__(16) float sW1t[100*28];   // [f][g], g padded 25->28
  __shared__ __align__(16) float sW2t[100*100];  // [f][c]
  __shared__ float sb1[100], sb2[100];
  __shared__ __align__(16) float sEA[4][NBE*28]; // per-wave [e][g]
  __shared__ __align__(16) float sT[4][NBE*100]; // per-wave [e][c]
  __shared__ float sEW[4][EPP];
  __shared__ float sCC[4][EPP];
  __shared__ int   sSRC[4][EPP];

  int tid = threadIdx.x, lane = tid & 63, wv = tid >> 6;

  // --- staging (coalesced global reads, scattered LDS writes) ---
  for (int idx = tid; idx < 2500; idx += 256){
    int g = idx/100, f = idx - g*100;
    sW1t[f*28+g] = W1[idx];
  }
  for (int idx = tid; idx < 300; idx += 256){   // zero the g=25..27 pad
    int f = idx/3, g = 25 + (idx - f*3);
    sW1t[f*28+g] = 0.0f;
  }
  for (int idx = tid; idx < 10000; idx += 256){
    int c = idx/100, f = idx - c*100;
    sW2t[f*100+c] = W2[idx];
  }
  if (tid < 100){ sb1[tid] = b1[tid]; sb2[tid] = b2[tid]; }

  int atom = blockIdx.x*4 + wv;
  if (lane < EPP){
    float d = ew[atom*EPP + lane];
    sEW[wv][lane]  = d;
    sCC[wv][lane]  = (d >= 5.9999995f) ? 0.0f
                     : 0.5f*(__cosf(d*0.52359877559f) + 1.0f);
    sSRC[wv][lane] = src[atom*EPP + lane];
  }
  __syncthreads();

  float* myEA = sEA[wv];
  float* myT  = sT[wv];
  int f0 = lane;
  bool f1v = lane < 36;
  int f1 = f1v ? lane + 64 : lane;   // invalid lanes duplicate f0 (masked stores)
  float acc0 = 0.0f, acc1 = 0.0f;

  #pragma unroll 1                   // CRITICAL: R1 spilled (256 VGPR) from full unroll
  for (int b = 0; b < 4; b++){
    // Phase A: gaussian features EA[8][28] for this batch (pad g>=25 -> 0)
    for (int idx = lane; idx < NBE*28; idx += 64){
      int e = idx/28, g = idx - e*28;
      float v = 0.0f;
      if (g < 25){
        float dd = sEW[wv][b*NBE+e] - 0.25f*(float)g;
        v = __expf(-8.0f*dd*dd);
      }
      myEA[idx] = v;
    }
    // Phase B: T = ssp(EA @ W1 + b1)   (no barrier: per-wave data)
    {
      float tv0[NBE], tv1[NBE];
      #pragma unroll
      for (int e = 0; e < NBE; e++){ tv0[e] = sb1[f0]; tv1[e] = sb1[f1]; }
      #pragma unroll
      for (int gb = 0; gb < 7; gb++){
        float4 w0 = *(const float4*)&sW1t[f0*28 + gb*4];
        float4 w1 = *(const float4*)&sW1t[f1*28 + gb*4];
        #pragma unroll
        for (int e = 0; e < NBE; e++){
          float4 ea = *(const float4*)&myEA[e*28 + gb*4];   // broadcast
          tv0[e] += ea.x*w0.x + ea.y*w0.y + ea.z*w0.z + ea.w*w0.w;
          tv1[e] += ea.x*w1.x + ea.y*w1.y + ea.z*w1.z + ea.w*w1.w;
        }
      }
      #pragma unroll
      for (int e = 0; e < NBE; e++){
        myT[e*100+f0] = sspf(tv0[e]);
        if (f1v) myT[e*100+f1] = sspf(tv1[e]);
      }
    }
    // Phase C: Wf = T @ W2 + b2
    float wf0[NBE], wf1[NBE];
    #pragma unroll
    for (int e = 0; e < NBE; e++){ wf0[e] = sb2[f0]; wf1[e] = sb2[f1]; }
    for (int cb = 0; cb < 25; cb++){
      float4 w0 = *(const float4*)&sW2t[f0*100 + cb*4];
      float4 w1 = *(const float4*)&sW2t[f1*100 + cb*4];
      #pragma unroll
      for (int e = 0; e < NBE; e++){
        float4 t = *(const float4*)&myT[e*100 + cb*4];      // broadcast
        wf0[e] += t.x*w0.x + t.y*w0.y + t.z*w0.z + t.w*w0.w;
        wf1[e] += t.x*w1.x + t.y*w1.y + t.z*w1.z + t.w*w1.w;
      }
    }
    // Phase D: msg = x1[src] * cc * Wf, accumulate (x1 rows are L2-hot)
    #pragma unroll
    for (int e = 0; e < NBE; e++){
      int ei = b*NBE + e;
      float cc = sCC[wv][ei];
      const float* xr = x1 + (size_t)sSRC[wv][ei]*FEAT;
      acc0 += xr[f0]*(cc*wf0[e]);
      acc1 += xr[f1]*(cc*wf1[e]);
    }
  }
  agg[atom*FEAT+f0] = acc0;
  if (f1v) agg[atom*FEAT+f1] = acc1;
}

// ---------------------------------------------------------------------------
// Node-side linear: Y = op(X @ W [+ b]). MODE 0: Y = X@W. MODE 1: Y = ssp(X@W+b).
// MODE 2: Y += X@W + b (residual h update). Wave handles 8 atoms; W^T in LDS.
// ---------------------------------------------------------------------------
template<int MODE>
__global__ __launch_bounds__(256) void node_linear(
    const float* __restrict__ X, const float* __restrict__ W,
    const float* __restrict__ bias, float* __restrict__ Y)
{
  __shared__ __align__(16) float sWt[100*100];   // [f][c]
  __shared__ float sB[100];
  __shared__ __align__(16) float sX[4][8*100];
  int tid = threadIdx.x, lane = tid & 63, wv = tid >> 6;
  for (int idx = tid; idx < 10000; idx += 256){
    int c = idx/100, f = idx - c*100;
    sWt[f*100+c] = W[idx];
  }
  if (tid < 100){
    if constexpr (MODE == 0) sB[tid] = 0.0f;
    else                     sB[tid] = bias[tid];
  }
  __syncthreads();
  int base = (blockIdx.x*4 + wv)*8;
  const float4* xg = (const float4*)(X + base*FEAT);
  for (int idx = lane; idx < 200; idx += 64)
    ((float4*)sX[wv])[idx] = xg[idx];
  int f0 = lane;
  bool f1v = lane < 36;
  int f1 = f1v ? lane + 64 : lane;
  float a0[8], a1[8];
  #pragma unroll
  for (int a = 0; a < 8; a++){ a0[a] = sB[f0]; a1[a] = sB[f1]; }
  for (int cb = 0; cb < 25; cb++){
    float4 w0 = *(const float4*)&sWt[f0*100 + cb*4];
    float4 w1 = *(const float4*)&sWt[f1*100 + cb*4];
    #pragma unroll
    for (int a = 0; a < 8; a++){
      float4 x = *(const float4*)&sX[wv][a*100 + cb*4];    // broadcast
      a0[a] += x.x*w0.x + x.y*w0.y + x.z*w0.z + x.w*w0.w;
      a1[a] += x.x*w1.x + x.y*w1.y + x.z*w1.z + x.w*w1.w;
    }
  }
  #pragma unroll
  for (int a = 0; a < 8; a++){
    int row = (base+a)*FEAT;
    float v0 = a0[a], v1 = a1[a];
    if constexpr (MODE == 1){ v0 = sspf(v0); v1 = sspf(v1); }
    if constexpr (MODE == 2){
      Y[row+f0] += v0;
      if (f1v) Y[row+f1] += v1;
    } else {
      Y[row+f0] = v0;
      if (f1v) Y[row+f1] = v1;
    }
  }
}

// ---------------------------------------------------------------------------
// Readout: per molecule (32 atoms): u = ssp(h@w1+b1) [50], pa = u@w2+b2,
// energy = sum over atoms. One wave per molecule.
// ---------------------------------------------------------------------------
__global__ __launch_bounds__(64) void readout(const float* __restrict__ h,
    const float* __restrict__ w1, const float* __restrict__ b1,
    const float* __restrict__ w2, const float* __restrict__ b2,
    float* __restrict__ out)
{
  __shared__ __align__(16) float sW1t[50*100];
  __shared__ __align__(16) float sX[32*100];
  __shared__ float sU[32*52];
  __shared__ float sPA[32];
  __shared__ float sw2[50];
  int lane = threadIdx.x;
  int mol = blockIdx.x;
  for (int idx = lane; idx < 5000; idx += 64){
    int c = idx/50, hf = idx - c*50;
    sW1t[hf*100+c] = w1[idx];
  }
  const float4* xg = (const float4*)(h + mol*32*FEAT);
  for (int idx = lane; idx < 800; idx += 64)
    ((float4*)sX)[idx] = xg[idx];
  if (lane < 50) sw2[lane] = w2[lane];
  __syncthreads();
  int hf = (lane < 50) ? lane : 0;
  bool hv = lane < 50;
  float acc[32];
  #pragma unroll
  for (int a = 0; a < 32; a++) acc[a] = 0.0f;
  for (int cb = 0; cb < 25; cb++){
    float4 w = *(const float4*)&sW1t[hf*100 + cb*4];
    #pragma unroll
    for (int a = 0; a < 32; a++){
      float4 x = *(const float4*)&sX[a*100 + cb*4];        // broadcast
      acc[a] += x.x*w.x + x.y*w.y + x.z*w.z + x.w*w.w;
    }
  }
  float bb = b1[hf];
  if (hv){
    #pragma unroll
    for (int a = 0; a < 32; a++) sU[a*52+hf] = sspf(acc[a] + bb);
  }
  __syncthreads();
  if (lane < 32){
    float pa = b2[0];
    for (int hfi = 0; hfi < 50; hfi++) pa += sU[lane*52+hfi]*sw2[hfi];
    sPA[lane] = pa;
  }
  __syncthreads();
  if (lane == 0){
    float s = 0.0f;
    #pragma unroll
    for (int a = 0; a < 32; a++) s += sPA[a];
    out[mol] = s;
  }
}

extern "C" void kernel_launch(void* const* d_in, const int* in_sizes, int n_in,
                              void* d_out, int out_size, void* d_ws, size_t ws_size,
                              hipStream_t stream)
{
  const int*   z      = (const int*)  d_in[0];
  const float* pos    = (const float*)d_in[1];
  /* d_in[2] = ptr: molecules are fixed 32-atom blocks; unused */
  const float* emb    = (const float*)d_in[3];
  const float* mlp_w1 = (const float*)d_in[4];
  const float* mlp_b1 = (const float*)d_in[5];
  const float* mlp_w2 = (const float*)d_in[6];
  const float* mlp_b2 = (const float*)d_in[7];
  const float* lin1_w = (const float*)d_in[8];
  const float* lin2_w = (const float*)d_in[9];
  const float* lin2_b = (const float*)d_in[10];
  const float* lin_w  = (const float*)d_in[11];
  const float* lin_b  = (const float*)d_in[12];
  const float* out_w1 = (const float*)d_in[13];
  const float* out_b1 = (const float*)d_in[14];
  const float* out_w2 = (const float*)d_in[15];
  const float* out_b2 = (const float*)d_in[16];

  float* ws   = (float*)d_ws;           // total ~15.2 MB
  float* ew   = ws;                     // [NA*EPP]
  int*   src  = (int*)(ew + NA*EPP);    // [NA*EPP]
  float* h    = (float*)(src + NA*EPP); // [NA*FEAT]
  float* x1   = h   + NA*FEAT;          // [NA*FEAT]
  float* agg  = x1  + NA*FEAT;          // [NA*FEAT]
  float* tmp  = agg + NA*FEAT;          // [NA*FEAT]

  build_graph<<<NA/64, 64, 0, stream>>>(pos, src, ew);
  h_init<<<(NA*FEAT + 255)/256, 256, 0, stream>>>(z, emb, h);
  for (int l = 0; l < 4; l++){
    node_linear<0><<<256, 256, 0, stream>>>(h, lin1_w + l*10000, nullptr, x1);
    edge_kernel<<<NA/4, 256, 0, stream>>>(ew, src, x1,
        mlp_w1 + l*2500, mlp_b1 + l*100,
        mlp_w2 + l*10000, mlp_b2 + l*100, agg);
    node_linear<1><<<256, 256, 0, stream>>>(agg, lin2_w + l*10000, lin2_b + l*100, tmp);
    node_linear<2><<<256, 256, 0, stream>>>(tmp, lin_w  + l*10000, lin_b  + l*100, h);
  }
  readout<<<256, 64, 0, stream>>>(h, out_w1, out_b1, out_w2, out_b2, (float*)d_out);
}

// Round 3
// 717.843 us; speedup vs baseline: 8.9270x; 2.1811x over previous
//
#include <hip/hip_runtime.h>
#include <math.h>

#define NA   8192
#define FEAT 100
#define KNN  28
#define EPP  32              // edges per atom, padded (28 real + 4 dummy cc=0)

typedef _Float16 f16x8 __attribute__((ext_vector_type(8)));
typedef float    f32x4 __attribute__((ext_vector_type(4)));

__device__ __forceinline__ float sspf(float x){
  // shifted softplus: log(1+exp(x)) - log(2), stable form
  return fmaxf(x, 0.0f) + __logf(1.0f + __expf(-fabsf(x))) - 0.69314718056f;
}

// ---------------------------------------------------------------------------
// KNN graph: molecules are fixed 32-atom blocks. Per atom: distances to its 31
// peers (clamped to cutoff), keep the 28 smallest (drop self + 3 largest).
// Clamped (==6.0) edges have cc ~= 0 so tie selection is irrelevant.
// Emits 32 edges/atom; 4 dummies (ew=6 -> cc=0).
// ---------------------------------------------------------------------------
__global__ __launch_bounds__(64) void build_graph(const float* __restrict__ pos,
    int* __restrict__ src, float* __restrict__ ew)
{
  __shared__ float sp[64][3];
  int tid = threadIdx.x;
  int a = blockIdx.x*64 + tid;
  sp[tid][0] = pos[a*3+0];
  sp[tid][1] = pos[a*3+1];
  sp[tid][2] = pos[a*3+2];
  __syncthreads();
  int lb = tid & 32;
  int li = tid & 31;
  float px = sp[tid][0], py = sp[tid][1], pz = sp[tid][2];
  float d[32];
  #pragma unroll
  for (int j = 0; j < 32; j++){
    float dx = px - sp[lb+j][0];
    float dy = py - sp[lb+j][1];
    float dz = pz - sp[lb+j][2];
    float d2 = dx*dx + dy*dy + dz*dz;
    float dist = (d2 > 36.0f) ? 6.0f : sqrtf(d2);
    d[j] = (j == li) ? 1e30f : dist;
  }
  unsigned dropped = 0u;
  for (int r = 0; r < 4; r++){
    float mx = -1.0f; int mj = 0;
    #pragma unroll
    for (int j = 0; j < 32; j++){
      bool ok = !((dropped >> j) & 1u) && (d[j] > mx);
      mx = ok ? d[j] : mx;
      mj = ok ? j  : mj;
    }
    dropped |= (1u << mj);
  }
  int mol  = a & ~31;
  int base = a*EPP;
  int k = 0;
  #pragma unroll
  for (int j = 0; j < 32; j++){
    if ((dropped >> j) & 1u) continue;
    src[base+k] = mol + j;
    ew[base+k]  = d[j];
    k++;
  }
  #pragma unroll
  for (int k2 = KNN; k2 < EPP; k2++){
    src[base+k2] = a;
    ew[base+k2]  = 6.0f;
  }
}

__global__ __launch_bounds__(256) void h_init(const int* __restrict__ z,
    const float* __restrict__ emb, float* __restrict__ h)
{
  int idx = blockIdx.x*256 + threadIdx.x;
  if (idx < NA*FEAT){
    int a = idx/FEAT, f = idx - a*FEAT;
    h[idx] = emb[z[a]*FEAT + f];
  }
}

// ---------------------------------------------------------------------------
// MFMA edge kernel. One wave = one atom (M = 32 padded edges, 2 m-tiles).
// GEMM1: T = ssp(EA[32x32] @ W1[32x112] + b1)   (g 25->32, f 100->112 zero-pad)
// GEMM2: Wf = T[32x128] @ W2[128x112] + b2      (k 100->128 zero-pad)
// agg[i][f] = sum_e cc[e] * Wf[e][f] * x1[src[e]][f]
// v_mfma_f32_16x16x32_f16 layouts (m120/m89-verified):
//   A: m=lane&15, k=(lane>>4)*8+j   B: n=lane&15, k=(lane>>4)*8+j
//   C/D: n=lane&15, m=(lane>>4)*4+r
// EA computed in registers in A-layout (no LDS). W1/W2 staged in LDS in exact
// fragment order (lane*16B contiguous -> conflict-free b128). T does one LDS
// round-trip per 32-feat k-chunk (per-wave buffer -> no barriers in main loop).
// LDS: 28672(W2)+7168(W1)+14336(x1 f32)+10240(T)+1536+896 = 62848 B.
// ---------------------------------------------------------------------------
__global__ __launch_bounds__(256) void edge_kernel(
    const float* __restrict__ ew, const int* __restrict__ src,
    const float* __restrict__ x1,
    const float* __restrict__ W1, const float* __restrict__ b1,
    const float* __restrict__ W2, const float* __restrict__ b2,
    float* __restrict__ agg)
{
  __shared__ __align__(16) _Float16 sW1s[7*64*8];    // frag order [nt][lane][j]
  __shared__ __align__(16) _Float16 sW2s[28*64*8];   // frag order [kc*7+nt][lane][j]
  __shared__ __align__(16) float    sX1[32*112];     // molecule x1, fp32, zero-pad cols
  __shared__ __align__(16) _Float16 sT[4][32*40];    // per-wave T chunk [e][f'] (40-pad)
  __shared__ float sEW[4*32], sCC[4*32];
  __shared__ int   sSRC[4*32];
  __shared__ float sb1[112], sb2[112];

  int tid = threadIdx.x, lane = tid & 63, wv = tid >> 6;
  int q = lane >> 4, n = lane & 15;

  // ---- block staging ----
  for (int idx = tid; idx < 7*512; idx += 256){
    int nt = idx >> 9, r = idx & 511, L = r >> 3, j = r & 7;
    int g = ((L >> 4) << 3) + j;
    int f = nt*16 + (L & 15);
    sW1s[idx] = (_Float16)((g < 25 && f < FEAT) ? W1[g*FEAT + f] : 0.0f);
  }
  for (int idx = tid; idx < 28*512; idx += 256){
    int fi = idx >> 9, r = idx & 511, L = r >> 3, j = r & 7;
    int kc = fi / 7, nt = fi - kc*7;
    int k = kc*32 + ((L >> 4) << 3) + j;
    int f = nt*16 + (L & 15);
    sW2s[idx] = (_Float16)((k < FEAT && f < FEAT) ? W2[k*FEAT + f] : 0.0f);
  }
  int molbase = (blockIdx.x*4) & ~31;            // first atom of the molecule
  for (int idx = tid; idx < 32*112; idx += 256){
    int row = idx / 112, col = idx - row*112;
    sX1[idx] = (col < FEAT) ? x1[(molbase + row)*FEAT + col] : 0.0f;
  }
  for (int idx = tid; idx < 128; idx += 256){    // 4 atoms x 32 edges
    int a_loc = idx >> 5;
    int ge = (blockIdx.x*4 + a_loc)*EPP + (idx & 31);
    float d = ew[ge];
    sEW[idx]  = d;
    sCC[idx]  = (d >= 5.9999995f) ? 0.0f : 0.5f*(__cosf(d*0.52359877559f) + 1.0f);
    sSRC[idx] = src[ge] & 31;                    // molecule-local source index
  }
  if (tid < 112){
    sb1[tid] = (tid < FEAT) ? b1[tid] : 0.0f;
    sb2[tid] = (tid < FEAT) ? b2[tid] : 0.0f;
  }
  __syncthreads();

  int atom = blockIdx.x*4 + wv;
  _Float16* myT = sT[wv];

  // per-lane constants
  float cc_r[2][4]; int src_r[2][4];
  #pragma unroll
  for (int mt = 0; mt < 2; mt++)
    #pragma unroll
    for (int r = 0; r < 4; r++){
      int e = mt*16 + q*4 + r;
      cc_r[mt][r]  = sCC[wv*32 + e];
      src_r[mt][r] = sSRC[wv*32 + e];
    }
  float bias1[7], bias2[7];
  #pragma unroll
  for (int nt = 0; nt < 7; nt++){
    bias1[nt] = sb1[nt*16 + n];
    bias2[nt] = sb2[nt*16 + n];
  }
  // EA A-fragments in registers (A-layout: m = n, k = q*8+j)
  f16x8 eaA[2];
  #pragma unroll
  for (int mt = 0; mt < 2; mt++){
    float d = sEW[wv*32 + mt*16 + n];
    #pragma unroll
    for (int j = 0; j < 8; j++){
      int g = q*8 + j;
      float v = 0.0f;
      if (g < 25){
        float dd = d - 0.25f*(float)g;
        v = __expf(-8.0f*dd*dd);
      }
      eaA[mt][j] = (_Float16)v;
    }
  }

  f32x4 acc[2][7];
  #pragma unroll
  for (int mt = 0; mt < 2; mt++)
    #pragma unroll
    for (int nt = 0; nt < 7; nt++)
      acc[mt][nt] = (f32x4){0.0f, 0.0f, 0.0f, 0.0f};

  #pragma unroll 1
  for (int kc = 0; kc < 4; kc++){
    // --- GEMM1 for the 2 feature tiles of this k-chunk -> T chunk in LDS ---
    #pragma unroll
    for (int h = 0; h < 2; h++){
      int nt = kc*2 + h;
      if (nt < 7){
        f16x8 bf = *(const f16x8*)&sW1s[(nt*64 + lane)*8];
        #pragma unroll
        for (int mt = 0; mt < 2; mt++){
          f32x4 c = __builtin_amdgcn_mfma_f32_16x16x32_f16(eaA[mt], bf,
                      (f32x4){0.0f,0.0f,0.0f,0.0f}, 0, 0, 0);
          float bb = bias1[nt];
          #pragma unroll
          for (int r = 0; r < 4; r++){
            float t = sspf(c[r] + bb);
            myT[(mt*16 + q*4 + r)*40 + h*16 + n] = (_Float16)t;
          }
        }
      } else {
        // nt==7 pad tile (kc==3, upper 16 feats): zero-fill
        int row = lane & 31, half = lane >> 5;
        *(f16x8*)&myT[row*40 + 16 + half*8] = (f16x8){0,0,0,0,0,0,0,0};
      }
    }
    // --- GEMM2 partial for this k-chunk ---
    f16x8 aT[2];
    #pragma unroll
    for (int mt = 0; mt < 2; mt++)
      aT[mt] = *(const f16x8*)&myT[(mt*16 + n)*40 + q*8];
    #pragma unroll
    for (int nt = 0; nt < 7; nt++){
      f16x8 bf = *(const f16x8*)&sW2s[((kc*7 + nt)*64 + lane)*8];
      #pragma unroll
      for (int mt = 0; mt < 2; mt++)
        acc[mt][nt] = __builtin_amdgcn_mfma_f32_16x16x32_f16(aT[mt], bf,
                        acc[mt][nt], 0, 0, 0);
    }
  }

  // --- epilogue: bias, cutoff, x1 gather, aggregate over edges ---
  float aggv[7];
  #pragma unroll
  for (int nt = 0; nt < 7; nt++) aggv[nt] = 0.0f;
  #pragma unroll
  for (int mt = 0; mt < 2; mt++){
    #pragma unroll
    for (int nt = 0; nt < 7; nt++){
      f32x4 c = acc[mt][nt];
      #pragma unroll
      for (int r = 0; r < 4; r++){
        float wf = c[r] + bias2[nt];
        float ccwf = wf * cc_r[mt][r];
        float xv = sX1[src_r[mt][r]*112 + nt*16 + n];
        aggv[nt] += ccwf * xv;
      }
    }
  }
  #pragma unroll
  for (int nt = 0; nt < 7; nt++){
    aggv[nt] += __shfl_xor(aggv[nt], 16);
    aggv[nt] += __shfl_xor(aggv[nt], 32);
  }
  if (lane < 16){
    #pragma unroll
    for (int nt = 0; nt < 7; nt++){
      int f = nt*16 + lane;
      if (f < FEAT) agg[atom*FEAT + f] = aggv[nt];
    }
  }
}

// ---------------------------------------------------------------------------
// Node-side linear: Y = op(X @ W [+ b]). MODE 0: Y = X@W. MODE 1: Y = ssp(X@W+b).
// MODE 2: Y += X@W + b (residual h update). Wave handles 8 atoms; W^T in LDS.
// ---------------------------------------------------------------------------
template<int MODE>
__global__ __launch_bounds__(256) void node_linear(
    const float* __restrict__ X, const float* __restrict__ W,
    const float* __restrict__ bias, float* __restrict__ Y)
{
  __shared__ __align__(16) float sWt[100*100];   // [f][c]
  __shared__ float sB[100];
  __shared__ __align__(16) float sX[4][8*100];
  int tid = threadIdx.x, lane = tid & 63, wv = tid >> 6;
  for (int idx = tid; idx < 10000; idx += 256){
    int c = idx/100, f = idx - c*100;
    sWt[f*100+c] = W[idx];
  }
  if (tid < 100){
    if constexpr (MODE == 0) sB[tid] = 0.0f;
    else                     sB[tid] = bias[tid];
  }
  __syncthreads();
  int base = (blockIdx.x*4 + wv)*8;
  const float4* xg = (const float4*)(X + base*FEAT);
  for (int idx = lane; idx < 200; idx += 64)
    ((float4*)sX[wv])[idx] = xg[idx];
  int f0 = lane;
  bool f1v = lane < 36;
  int f1 = f1v ? lane + 64 : lane;
  float a0[8], a1[8];
  #pragma unroll
  for (int a = 0; a < 8; a++){ a0[a] = sB[f0]; a1[a] = sB[f1]; }
  for (int cb = 0; cb < 25; cb++){
    float4 w0 = *(const float4*)&sWt[f0*100 + cb*4];
    float4 w1 = *(const float4*)&sWt[f1*100 + cb*4];
    #pragma unroll
    for (int a = 0; a < 8; a++){
      float4 x = *(const float4*)&sX[wv][a*100 + cb*4];
      a0[a] += x.x*w0.x + x.y*w0.y + x.z*w0.z + x.w*w0.w;
      a1[a] += x.x*w1.x + x.y*w1.y + x.z*w1.z + x.w*w1.w;
    }
  }
  #pragma unroll
  for (int a = 0; a < 8; a++){
    int row = (base+a)*FEAT;
    float v0 = a0[a], v1 = a1[a];
    if constexpr (MODE == 1){ v0 = sspf(v0); v1 = sspf(v1); }
    if constexpr (MODE == 2){
      Y[row+f0] += v0;
      if (f1v) Y[row+f1] += v1;
    } else {
      Y[row+f0] = v0;
      if (f1v) Y[row+f1] = v1;
    }
  }
}

// ---------------------------------------------------------------------------
// Readout: per molecule (32 atoms): u = ssp(h@w1+b1) [50], pa = u@w2+b2,
// energy = sum over atoms. One wave per molecule.
// ---------------------------------------------------------------------------
__global__ __launch_bounds__(64) void readout(const float* __restrict__ h,
    const float* __restrict__ w1, const float* __restrict__ b1,
    const float* __restrict__ w2, const float* __restrict__ b2,
    float* __restrict__ out)
{
  __shared__ __align__(16) float sW1t[50*100];
  __shared__ __align__(16) float sX[32*100];
  __shared__ float sU[32*52];
  __shared__ float sPA[32];
  __shared__ float sw2[50];
  int lane = threadIdx.x;
  int mol = blockIdx.x;
  for (int idx = lane; idx < 5000; idx += 64){
    int c = idx/50, hf = idx - c*50;
    sW1t[hf*100+c] = w1[idx];
  }
  const float4* xg = (const float4*)(h + mol*32*FEAT);
  for (int idx = lane; idx < 800; idx += 64)
    ((float4*)sX)[idx] = xg[idx];
  if (lane < 50) sw2[lane] = w2[lane];
  __syncthreads();
  int hf = (lane < 50) ? lane : 0;
  bool hv = lane < 50;
  float acc[32];
  #pragma unroll
  for (int a = 0; a < 32; a++) acc[a] = 0.0f;
  for (int cb = 0; cb < 25; cb++){
    float4 w = *(const float4*)&sW1t[hf*100 + cb*4];
    #pragma unroll
    for (int a = 0; a < 32; a++){
      float4 x = *(const float4*)&sX[a*100 + cb*4];
      acc[a] += x.x*w.x + x.y*w.y + x.z*w.z + x.w*w.w;
    }
  }
  float bb = b1[hf];
  if (hv){
    #pragma unroll
    for (int a = 0; a < 32; a++) sU[a*52+hf] = sspf(acc[a] + bb);
  }
  __syncthreads();
  if (lane < 32){
    float pa = b2[0];
    for (int hfi = 0; hfi < 50; hfi++) pa += sU[lane*52+hfi]*sw2[hfi];
    sPA[lane] = pa;
  }
  __syncthreads();
  if (lane == 0){
    float s = 0.0f;
    #pragma unroll
    for (int a = 0; a < 32; a++) s += sPA[a];
    out[mol] = s;
  }
}

extern "C" void kernel_launch(void* const* d_in, const int* in_sizes, int n_in,
                              void* d_out, int out_size, void* d_ws, size_t ws_size,
                              hipStream_t stream)
{
  const int*   z      = (const int*)  d_in[0];
  const float* pos    = (const float*)d_in[1];
  /* d_in[2] = ptr: molecules are fixed 32-atom blocks; unused */
  const float* emb    = (const float*)d_in[3];
  const float* mlp_w1 = (const float*)d_in[4];
  const float* mlp_b1 = (const float*)d_in[5];
  const float* mlp_w2 = (const float*)d_in[6];
  const float* mlp_b2 = (const float*)d_in[7];
  const float* lin1_w = (const float*)d_in[8];
  const float* lin2_w = (const float*)d_in[9];
  const float* lin2_b = (const float*)d_in[10];
  const float* lin_w  = (const float*)d_in[11];
  const float* lin_b  = (const float*)d_in[12];
  const float* out_w1 = (const float*)d_in[13];
  const float* out_b1 = (const float*)d_in[14];
  const float* out_w2 = (const float*)d_in[15];
  const float* out_b2 = (const float*)d_in[16];

  float* ws   = (float*)d_ws;
  float* ew   = ws;                     // [NA*EPP]
  int*   src  = (int*)(ew + NA*EPP);    // [NA*EPP]
  float* h    = (float*)(src + NA*EPP); // [NA*FEAT]
  float* x1   = h   + NA*FEAT;          // [NA*FEAT]
  float* agg  = x1  + NA*FEAT;          // [NA*FEAT]
  float* tmp  = agg + NA*FEAT;          // [NA*FEAT]

  build_graph<<<NA/64, 64, 0, stream>>>(pos, src, ew);
  h_init<<<(NA*FEAT + 255)/256, 256, 0, stream>>>(z, emb, h);
  for (int l = 0; l < 4; l++){
    node_linear<0><<<256, 256, 0, stream>>>(h, lin1_w + l*10000, nullptr, x1);
    edge_kernel<<<NA/4, 256, 0, stream>>>(ew, src, x1,
        mlp_w1 + l*2500, mlp_b1 + l*100,
        mlp_w2 + l*10000, mlp_b2 + l*100, agg);
    node_linear<1><<<256, 256, 0, stream>>>(agg, lin2_w + l*10000, lin2_b + l*100, tmp);
    node_linear<2><<<256, 256, 0, stream>>>(tmp, lin_w  + l*10000, lin_b  + l*100, h);
  }
  readout<<<256, 64, 0, stream>>>(h, out_w1, out_b1, out_w2, out_b2, (float*)d_out);
}

// Round 4
// 235.228 us; speedup vs baseline: 27.2424x; 3.0517x over previous
//
#include <hip/hip_runtime.h>
#include <math.h>

#define APM   32
#define NMOL  256
#define FEAT  100
#define NPAD  112
#define KPAD  128
#define LAYERS 4

typedef _Float16 f16x8 __attribute__((ext_vector_type(8)));
typedef float    f32x4 __attribute__((ext_vector_type(4)));

// per-layer f16 frag-weight block layout in ws (element offsets)
#define L1F_OFF 0        // lin1f  14336
#define W1F_OFF 14336    // W1f    3584
#define W2F_OFF 17920    // W2f    14336
#define L2F_OFF 32256    // lin2f  14336
#define LVF_OFF 46592    // linf   14336
#define LWTOT   60928    // per layer
#define WTOTAL  (4*LWTOT) // 243712

__device__ __forceinline__ float sspf(float x){
  // shifted softplus: log(1+exp(x)) - log(2)
  return fmaxf(x, 0.0f) + __logf(1.0f + __expf(-fabsf(x))) - 0.69314718056f;
}

// ---------------------------------------------------------------------------
// One-time weight conversion into f16 MFMA B-fragment order:
//   Bf[((kc*7+nt)*64 + lane)*8 + j] = W[k][f],  k = kc*32+(lane>>4)*8+j,
//   f = nt*16+(lane&15); zero outside (Kdim, 100). Validated layout (R3).
// ---------------------------------------------------------------------------
__global__ __launch_bounds__(256) void prep_weights(
    const float* __restrict__ mlp_w1, const float* __restrict__ mlp_w2,
    const float* __restrict__ lin1_w, const float* __restrict__ lin2_w,
    const float* __restrict__ lin_w,  _Float16* __restrict__ out)
{
  int gid = blockIdx.x*256 + threadIdx.x;      // < 243712 exactly
  int l = gid / LWTOT;
  int r = gid - l*LWTOT;
  const float* W; int Kdim; int e;
  if (r < 14336)      { W = lin1_w + l*10000; Kdim = 100; e = r; }
  else if (r < 17920) { W = mlp_w1 + l*2500;  Kdim = 25;  e = r - 14336; }
  else if (r < 32256) { W = mlp_w2 + l*10000; Kdim = 100; e = r - 17920; }
  else if (r < 46592) { W = lin2_w + l*10000; Kdim = 100; e = r - 32256; }
  else                { W = lin_w  + l*10000; Kdim = 100; e = r - 46592; }
  int j = e & 7, L = (e >> 3) & 63, tile = e >> 9;
  int kc = tile / 7, nt = tile - kc*7;
  int k = kc*32 + ((L >> 4) << 3) + j;
  int f = nt*16 + (L & 15);
  float v = (k < Kdim && f < FEAT) ? W[k*FEAT + f] : 0.0f;
  out[gid] = (_Float16)v;
}

__device__ __forceinline__ void cpw(_Float16* dst, const _Float16* src, int n16){
  const uint4* s = (const uint4*)src;
  uint4* d = (uint4*)dst;
  for (int i = threadIdx.x; i < n16; i += 512) d[i] = s[i];
}

// ---------------------------------------------------------------------------
// Whole network per molecule in one block: graph + emb + 4 interaction layers
// + readout. 512 threads = 8 waves. All intermediates in LDS (~113 KB).
// MFMA layouts (validated in R3): A: m=lane&15,k=(lane>>4)*8+j ; C/D:
// n=lane&15, m=(lane>>4)*4+r.
// ---------------------------------------------------------------------------
__global__ __launch_bounds__(512, 2) void schnet_mega(
    const int* __restrict__ z, const float* __restrict__ pos,
    const float* __restrict__ emb, const _Float16* __restrict__ wf,
    const float* __restrict__ mlp_b1, const float* __restrict__ mlp_b2,
    const float* __restrict__ lin2_b, const float* __restrict__ lin_b,
    const float* __restrict__ out_w1, const float* __restrict__ out_b1,
    const float* __restrict__ out_w2, const float* __restrict__ out_b2,
    float* __restrict__ out)
{
  __shared__ __align__(16) _Float16 sWA[17920];     // weight staging (35840 B)
  __shared__ __align__(16) _Float16 sAf[APM*136];   // A-frag f16 buffer (h/agg)
  __shared__ __align__(16) _Float16 sBf[APM*136];   // A-frag f16 buffer (t2)
  __shared__ __align__(16) float    sX1[APM*113];   // x1 fp32 (stride 113)
  __shared__ __align__(16) float    sH [APM*NPAD];  // h state fp32
  __shared__ __align__(16) _Float16 sT[8][32*40];   // per-wave T chunk
  __shared__ float sD [APM*33];
  __shared__ float sCC[APM*33];
  __shared__ float sB1m[NPAD], sB2m[NPAD], sB2l[NPAD], sBlv[NPAD];
  __shared__ float sPos[APM*3];
  __shared__ float sPart[8];

  int tid = threadIdx.x, lane = tid & 63, wv = tid >> 6;
  int q = lane >> 4, n = lane & 15;
  int mol = blockIdx.x, mb = mol*APM;

  // ---------------- init ----------------
  if (tid < 96) sPos[tid] = pos[mb*3 + tid];
  if (tid >= 96 && tid < 144){                 // zero bias pads 100..111
    int w = (tid-96)/12, i = 100 + (tid-96)%12;
    (w==0 ? sB1m : w==1 ? sB2m : w==2 ? sB2l : sBlv)[i] = 0.0f;
  }
  { int r0 = tid >> 4, c0 = 112 + (tid & 15);  // zero sBf k-pad cols 112..127
    sBf[r0*136 + c0] = (_Float16)0.0f; }
  for (int i = tid; i < APM*NPAD; i += 512){   // h init from embedding
    int r = i/NPAD, c = i - r*NPAD;
    sH[i] = (c < FEAT) ? emb[z[mb+r]*FEAT + c] : 0.0f;
  }
  __syncthreads();
  for (int p = tid; p < APM*APM; p += 512){    // distances + raw cutoff
    int i = p >> 5, j = p & 31;
    float dx = sPos[i*3+0]-sPos[j*3+0];
    float dy = sPos[i*3+1]-sPos[j*3+1];
    float dz = sPos[i*3+2]-sPos[j*3+2];
    float d2 = dx*dx + dy*dy + dz*dz;
    float d = (d2 > 36.0f) ? 6.0f : sqrtf(d2);
    sD[i*33+j]  = d;
    sCC[i*33+j] = 0.5f*(__cosf(d*0.52359877559f) + 1.0f);
  }
  __syncthreads();
  if (tid < APM){                              // drop self + 3 farthest: cc=0
    float dd[32];
    #pragma unroll
    for (int j = 0; j < 32; j++) dd[j] = sD[tid*33+j];
    dd[tid] = 1e30f;
    unsigned dropped = 0u;
    for (int rr = 0; rr < 4; rr++){
      float mx = -1.0f; int mj = 0;
      #pragma unroll
      for (int j = 0; j < 32; j++){
        bool ok = !((dropped>>j)&1u) && (dd[j] > mx);
        mx = ok ? dd[j] : mx;  mj = ok ? j : mj;
      }
      dropped |= 1u << mj;
    }
    #pragma unroll
    for (int j = 0; j < 32; j++)
      if ((dropped>>j)&1u) sCC[tid*33+j] = 0.0f;
  }
  __syncthreads();

  // ---------------- interaction layers ----------------
  for (int l = 0; l < LAYERS; l++){
    const _Float16* wl = wf + l*LWTOT;
    // stage lin1f + biases; cvt sH -> sAf (f16 A-frag rows, k-pad zeros)
    cpw(sWA, wl + L1F_OFF, 14336/8);
    if (tid < 400){
      int w = tid/100, i = tid - w*100;
      float v = (w==0 ? mlp_b1 : w==1 ? mlp_b2 : w==2 ? lin2_b : lin_b)[l*FEAT + i];
      (w==0 ? sB1m : w==1 ? sB2m : w==2 ? sB2l : sBlv)[i] = v;
    }
    for (int i = tid; i < APM*KPAD; i += 512){
      int r = i >> 7, c = i & 127;
      sAf[r*136+c] = (c < NPAD) ? (_Float16)sH[r*NPAD+c] : (_Float16)0.0f;
    }
    __syncthreads();
    // ---- x1 = h @ lin1 -> sX1 fp32 ----
    for (int tau = wv; tau < 14; tau += 8){
      int mt = tau/7, nt = tau - mt*7;
      f32x4 acc = {0.0f,0.0f,0.0f,0.0f};
      #pragma unroll
      for (int kc = 0; kc < 4; kc++){
        f16x8 a = *(const f16x8*)&sAf[(mt*16+n)*136 + kc*32 + q*8];
        f16x8 b = *(const f16x8*)&sWA[((kc*7+nt)*64 + lane)*8];
        acc = __builtin_amdgcn_mfma_f32_16x16x32_f16(a, b, acc, 0, 0, 0);
      }
      #pragma unroll
      for (int r = 0; r < 4; r++)
        sX1[(mt*16+q*4+r)*113 + nt*16+n] = acc[r];
    }
    __syncthreads();
    cpw(sWA, wl + W1F_OFF, (3584+14336)/8);   // W1f @0, W2f @3584 (contiguous)
    __syncthreads();
    // ---- edge MLP + CFConv agg: wave handles atoms wv*4..wv*4+3 ----
    {
      _Float16* myT = sT[wv];
      #pragma unroll 1
      for (int t = 0; t < 4; t++){
        int a = wv*4 + t;
        f16x8 eaA[2];                          // gaussian A-frags
        #pragma unroll
        for (int mt = 0; mt < 2; mt++){
          float d = sD[a*33 + mt*16 + n];
          #pragma unroll
          for (int j = 0; j < 8; j++){
            int g = q*8 + j;
            float dd2 = d - 0.25f*(float)g;
            float v = (g < 25) ? __expf(-8.0f*dd2*dd2) : 0.0f;
            eaA[mt][j] = (_Float16)v;
          }
        }
        f32x4 acc2[2][7];
        #pragma unroll
        for (int mt = 0; mt < 2; mt++)
          #pragma unroll
          for (int nt = 0; nt < 7; nt++)
            acc2[mt][nt] = (f32x4){0.0f,0.0f,0.0f,0.0f};
        #pragma unroll 1
        for (int kc = 0; kc < 4; kc++){
          #pragma unroll
          for (int hh = 0; hh < 2; hh++){
            int nt1 = kc*2 + hh;
            if (nt1 < 7){
              f16x8 bf = *(const f16x8*)&sWA[(nt1*64 + lane)*8];
              float bb = sB1m[nt1*16 + n];
              #pragma unroll
              for (int mt = 0; mt < 2; mt++){
                f32x4 c = __builtin_amdgcn_mfma_f32_16x16x32_f16(eaA[mt], bf,
                            (f32x4){0.0f,0.0f,0.0f,0.0f}, 0, 0, 0);
                #pragma unroll
                for (int r = 0; r < 4; r++)
                  myT[(mt*16+q*4+r)*40 + hh*16 + n] = (_Float16)sspf(c[r] + bb);
              }
            } else {  // kc==3,hh==1: zero T pad cols 16..31 of this chunk
              int row = lane & 31, half = lane >> 5;
              *(f16x8*)&myT[row*40 + 16 + half*8] =
                  (f16x8){0,0,0,0,0,0,0,0};
            }
          }
          f16x8 aT[2];
          #pragma unroll
          for (int mt = 0; mt < 2; mt++)
            aT[mt] = *(const f16x8*)&myT[(mt*16+n)*40 + q*8];
          #pragma unroll
          for (int nt = 0; nt < 7; nt++){
            f16x8 bf = *(const f16x8*)&sWA[3584 + ((kc*7+nt)*64 + lane)*8];
            #pragma unroll
            for (int mt = 0; mt < 2; mt++)
              acc2[mt][nt] = __builtin_amdgcn_mfma_f32_16x16x32_f16(
                               aT[mt], bf, acc2[mt][nt], 0, 0, 0);
          }
        }
        // epilogue: Wf=acc+b2, msg = cc*Wf*x1[e], reduce over edges
        float aggv[7];
        #pragma unroll
        for (int nt = 0; nt < 7; nt++) aggv[nt] = 0.0f;
        #pragma unroll
        for (int mt = 0; mt < 2; mt++){
          #pragma unroll
          for (int r = 0; r < 4; r++){
            int e = mt*16 + q*4 + r;
            float cc = sCC[a*33 + e];
            #pragma unroll
            for (int nt = 0; nt < 7; nt++){
              float wfv = acc2[mt][nt][r] + sB2m[nt*16+n];
              aggv[nt] += (cc*wfv) * sX1[e*113 + nt*16+n];
            }
          }
        }
        #pragma unroll
        for (int nt = 0; nt < 7; nt++){
          aggv[nt] += __shfl_xor(aggv[nt], 16);
          aggv[nt] += __shfl_xor(aggv[nt], 32);
        }
        if (lane < 16){
          #pragma unroll
          for (int nt = 0; nt < 7; nt++)
            sAf[a*136 + nt*16 + lane] = (_Float16)aggv[nt];
          sAf[a*136 + 112 + lane] = (_Float16)0.0f;   // k-pad for next GEMM
        }
      }
    }
    __syncthreads();
    cpw(sWA, wl + L2F_OFF, 14336/8);
    __syncthreads();
    // ---- t2 = ssp(agg @ lin2 + b2l) -> sBf f16 ----
    for (int tau = wv; tau < 14; tau += 8){
      int mt = tau/7, nt = tau - mt*7;
      f32x4 acc = {0.0f,0.0f,0.0f,0.0f};
      #pragma unroll
      for (int kc = 0; kc < 4; kc++){
        f16x8 a = *(const f16x8*)&sAf[(mt*16+n)*136 + kc*32 + q*8];
        f16x8 b = *(const f16x8*)&sWA[((kc*7+nt)*64 + lane)*8];
        acc = __builtin_amdgcn_mfma_f32_16x16x32_f16(a, b, acc, 0, 0, 0);
      }
      float bb = sB2l[nt*16+n];
      #pragma unroll
      for (int r = 0; r < 4; r++)
        sBf[(mt*16+q*4+r)*136 + nt*16+n] = (_Float16)sspf(acc[r] + bb);
    }
    __syncthreads();
    cpw(sWA, wl + LVF_OFF, 14336/8);
    __syncthreads();
    // ---- v = t2 @ lin + bl ; h += v ----
    for (int tau = wv; tau < 14; tau += 8){
      int mt = tau/7, nt = tau - mt*7;
      f32x4 acc = {0.0f,0.0f,0.0f,0.0f};
      #pragma unroll
      for (int kc = 0; kc < 4; kc++){
        f16x8 a = *(const f16x8*)&sBf[(mt*16+n)*136 + kc*32 + q*8];
        f16x8 b = *(const f16x8*)&sWA[((kc*7+nt)*64 + lane)*8];
        acc = __builtin_amdgcn_mfma_f32_16x16x32_f16(a, b, acc, 0, 0, 0);
      }
      int f = nt*16 + n;
      if (f < FEAT){
        float bb = sBlv[f];
        #pragma unroll
        for (int r = 0; r < 4; r++)
          sH[(mt*16+q*4+r)*NPAD + f] += acc[r] + bb;
      }
    }
    __syncthreads();
  }

  // ---------------- readout ----------------
  float* rw = (float*)sWA;                     // out_w1 [100][50] fp32
  for (int i = tid; i < 5000; i += 512) rw[i] = out_w1[i];
  if (tid < 50){ sB1m[tid] = out_b1[tid]; sB2m[tid] = out_w2[tid]; }
  __syncthreads();
  float ob2 = out_b2[0];
  float partial = 0.0f;
  for (int t = 0; t < 4; t++){
    int a = wv*4 + t;
    float u = 0.0f;
    if (lane < 50){
      u = sB1m[lane];
      #pragma unroll 4
      for (int c = 0; c < FEAT; c++)
        u += sH[a*NPAD + c] * rw[c*50 + lane];
      u = sspf(u) * sB2m[lane];
    }
    #pragma unroll
    for (int s = 1; s < 64; s <<= 1) u += __shfl_xor(u, s);
    partial += u + ob2;
  }
  if (lane == 0) sPart[wv] = partial;
  __syncthreads();
  if (tid == 0){
    float s = 0.0f;
    #pragma unroll
    for (int i = 0; i < 8; i++) s += sPart[i];
    out[mol] = s;
  }
}

extern "C" void kernel_launch(void* const* d_in, const int* in_sizes, int n_in,
                              void* d_out, int out_size, void* d_ws, size_t ws_size,
                              hipStream_t stream)
{
  const int*   z      = (const int*)  d_in[0];
  const float* pos    = (const float*)d_in[1];
  /* d_in[2] = ptr: molecules are fixed 32-atom blocks; unused */
  const float* emb    = (const float*)d_in[3];
  const float* mlp_w1 = (const float*)d_in[4];
  const float* mlp_b1 = (const float*)d_in[5];
  const float* mlp_w2 = (const float*)d_in[6];
  const float* mlp_b2 = (const float*)d_in[7];
  const float* lin1_w = (const float*)d_in[8];
  const float* lin2_w = (const float*)d_in[9];
  const float* lin2_b = (const float*)d_in[10];
  const float* lin_w  = (const float*)d_in[11];
  const float* lin_b  = (const float*)d_in[12];
  const float* out_w1 = (const float*)d_in[13];
  const float* out_b1 = (const float*)d_in[14];
  const float* out_w2 = (const float*)d_in[15];
  const float* out_b2 = (const float*)d_in[16];

  _Float16* wfrag = (_Float16*)d_ws;           // 243712 f16 = 487 KB

  prep_weights<<<WTOTAL/256, 256, 0, stream>>>(mlp_w1, mlp_w2, lin1_w,
                                               lin2_w, lin_w, wfrag);
  schnet_mega<<<NMOL, 512, 0, stream>>>(z, pos, emb, wfrag,
      mlp_b1, mlp_b2, lin2_b, lin_b,
      out_w1, out_b1, out_w2, out_b2, (float*)d_out);
}